// Round 1
// baseline (6226.451 us; speedup 1.0000x reference)
//
#include <hip/hip_runtime.h>

// Problem constants: S=512, M=512, B=8, NH=16, HD=64, H=1024, K=1024,
// LAYERS=2, TOTAL_LEN=1536.
#define OUT_OFF 4194304      // B*S*H floats (part-1 of d_out)
#define NM_ELEMS 25165824    // 2*8*1536*1024 floats (part-2: new_mem)

static __device__ __forceinline__ float4 ld4(const float* p) {
  return *reinterpret_cast<const float4*>(p);
}
static __device__ __forceinline__ void st4(float* p, float4 v) {
  *reinterpret_cast<float4*>(p) = v;
}

// ---------------------------------------------------------------------------
// Tiled fp32 GEMM: C[rows x 1024] = A[rows x 1024] @ W[1024 x 1024]
// MODE 0: plain A.
// MODE 1: A rows gathered from kvx = concat(memories slice, x) per batch.
// MODE 2: plain A, epilogue adds bias and writes BOTH d_out rows and the
//         new_mem slice.
// BM=BN=128, BK=16, 256 threads, 8x8 micro-tile per thread.
// ---------------------------------------------------------------------------
template<int MODE>
__global__ __launch_bounds__(256)
void gemm_k(const float* __restrict__ A, const float* __restrict__ mem,
            const float* __restrict__ W, const float* __restrict__ bias,
            const int* __restrict__ lp, const int* __restrict__ sp,
            float* __restrict__ C)
{
  __shared__ float As[16][132];   // [k][m], padded
  __shared__ float Bs[16][132];   // [k][n], padded
  const int tid = threadIdx.x;
  const int m0 = blockIdx.y * 128;
  const int n0 = blockIdx.x * 128;
  const int am = tid >> 1;          // 0..127  (A tile row)
  const int ak = (tid & 1) * 8;     // 0 or 8  (A tile k base)
  const int bk = tid >> 4;          // 0..15   (B tile k)
  const int bn = (tid & 15) * 8;    // B tile col base
  const int tm = tid & 15;          // micro-tile row group
  const int tn = tid >> 4;          // micro-tile col group

  const float* Arow;
  if (MODE == 1) {
    const int r  = m0 + am;         // global kvx row, r = j*? -- here r in [0,8192)
    const int bb = r >> 10;         // batch
    const int j  = r & 1023;        // position in K
    const int layer = lp[0];
    const int seg   = sp[0];
    if (j < 512)
      Arow = mem + (((size_t)layer * 8 + bb) * 1536 + (size_t)seg * 512 + j) * 1024;
    else
      Arow = A + ((size_t)bb * 512 + (j - 512)) * 1024;
  } else {
    Arow = A + (size_t)(m0 + am) * 1024;
  }

  float acc[8][8] = {};

  for (int k0 = 0; k0 < 1024; k0 += 16) {
    const float4 a0 = ld4(Arow + k0 + ak);
    const float4 a1 = ld4(Arow + k0 + ak + 4);
    const float* wr = W + (size_t)(k0 + bk) * 1024 + n0 + bn;
    const float4 b0 = ld4(wr);
    const float4 b1 = ld4(wr + 4);
    __syncthreads();
    As[ak+0][am] = a0.x; As[ak+1][am] = a0.y; As[ak+2][am] = a0.z; As[ak+3][am] = a0.w;
    As[ak+4][am] = a1.x; As[ak+5][am] = a1.y; As[ak+6][am] = a1.z; As[ak+7][am] = a1.w;
    st4(&Bs[bk][bn],   b0);
    st4(&Bs[bk][bn+4], b1);
    __syncthreads();
    #pragma unroll
    for (int k = 0; k < 16; ++k) {
      float a[8], b8[8];
      *reinterpret_cast<float4*>(&a[0])  = ld4(&As[k][tm*8]);
      *reinterpret_cast<float4*>(&a[4])  = ld4(&As[k][tm*8+4]);
      *reinterpret_cast<float4*>(&b8[0]) = ld4(&Bs[k][tn*8]);
      *reinterpret_cast<float4*>(&b8[4]) = ld4(&Bs[k][tn*8+4]);
      #pragma unroll
      for (int ii = 0; ii < 8; ++ii)
        #pragma unroll
        for (int jj = 0; jj < 8; ++jj)
          acc[ii][jj] = fmaf(a[ii], b8[jj], acc[ii][jj]);
    }
  }

  if (MODE == 2) {
    const int layer = lp[0];
    const int seg   = sp[0];
    #pragma unroll
    for (int ii = 0; ii < 8; ++ii) {
      const int row = m0 + tm*8 + ii;      // r = b2*S + s2  (== i*B + b flat)
      const int b2  = row >> 9;
      const int s2  = row & 511;
      const size_t nmrow =
          (((size_t)layer * 8 + b2) * 1536 + 512 + (size_t)seg * 512 + s2) * 1024;
      #pragma unroll
      for (int jq = 0; jq < 2; ++jq) {
        const int col = n0 + tn*8 + jq*4;
        const float4 bi = ld4(bias + col);
        float4 o4;
        o4.x = acc[ii][jq*4+0] + bi.x;
        o4.y = acc[ii][jq*4+1] + bi.y;
        o4.z = acc[ii][jq*4+2] + bi.z;
        o4.w = acc[ii][jq*4+3] + bi.w;
        st4(C + (size_t)row * 1024 + col, o4);
        st4(C + OUT_OFF + nmrow + col, o4);
      }
    }
  } else {
    #pragma unroll
    for (int ii = 0; ii < 8; ++ii) {
      const int row = m0 + tm*8 + ii;
      #pragma unroll
      for (int jq = 0; jq < 2; ++jq) {
        const int col = n0 + tn*8 + jq*4;
        float4 o4;
        o4.x = acc[ii][jq*4+0]; o4.y = acc[ii][jq*4+1];
        o4.z = acc[ii][jq*4+2]; o4.w = acc[ii][jq*4+3];
        st4(C + (size_t)row * 1024 + col, o4);
      }
    }
  }
}

// ---------------------------------------------------------------------------
// W2[p][n] = sum_d (v[n,d]-u[n,d]) * Pr[p, n*64+d]   (1024 x 16)
// ---------------------------------------------------------------------------
__global__ __launch_bounds__(256)
void w2_k(const float* __restrict__ Pr, const float* __restrict__ u,
          const float* __restrict__ v, float* __restrict__ W2)
{
  const int t = blockIdx.x * 256 + threadIdx.x;   // 0..16383
  const int p = t >> 4;
  const int n = t & 15;
  const float* rb = Pr + (size_t)p * 1024 + n * 64;
  const float* ub = u + n * 64;
  const float* vb = v + n * 64;
  float s0 = 0, s1 = 0, s2 = 0, s3 = 0;
  #pragma unroll
  for (int d = 0; d < 64; d += 4) {
    float4 r4 = ld4(rb + d);
    float4 u4 = ld4(ub + d);
    float4 v4 = ld4(vb + d);
    s0 = fmaf(v4.x - u4.x, r4.x, s0);
    s1 = fmaf(v4.y - u4.y, r4.y, s1);
    s2 = fmaf(v4.z - u4.z, r4.z, s2);
    s3 = fmaf(v4.w - u4.w, r4.w, s3);
  }
  W2[t] = (s0 + s1) + (s2 + s3);
}

// ---------------------------------------------------------------------------
// Fused attention: logits (ac + bd_shifted)/8, softmax over the 16 HEADS,
// then PV accumulate. One thread = (query i, head n); block = 16 i x 16 n,
// grid = (32 i-tiles, 8 batches). Softmax = shuffle over 16 lanes.
// ---------------------------------------------------------------------------
__global__ __launch_bounds__(256, 2)
void attn_k(const float* __restrict__ Pq, const float* __restrict__ Pk,
            const float* __restrict__ Pv, const float* __restrict__ Pr,
            const float* __restrict__ W2, const float* __restrict__ u,
            float* __restrict__ O)
{
  const int b  = blockIdx.y;
  const int i0 = blockIdx.x * 16;
  const int il = threadIdx.x >> 4;
  const int n  = threadIdx.x & 15;
  const int i  = i0 + il;

  const float* qp = Pq + ((size_t)(i * 8 + b)) * 1024 + n * 64;
  const float* up = u + n * 64;
  float qu[64], o[64];
  #pragma unroll
  for (int d = 0; d < 64; d += 4) {
    float4 q4 = ld4(qp + d);
    float4 u4 = ld4(up + d);
    qu[d+0] = q4.x + u4.x; qu[d+1] = q4.y + u4.y;
    qu[d+2] = q4.z + u4.z; qu[d+3] = q4.w + u4.w;
    o[d+0] = 0.f; o[d+1] = 0.f; o[d+2] = 0.f; o[d+3] = 0.f;
  }
  const int pbase = 511 - i;

  for (int j = 0; j < 1024; ++j) {
    const float* kb = Pk + ((size_t)(j * 8 + b)) * 1024 + n * 64;
    float ac0 = 0, ac1 = 0, ac2 = 0, ac3 = 0;
    #pragma unroll
    for (int d = 0; d < 64; d += 4) {
      float4 k4 = ld4(kb + d);
      ac0 = fmaf(qu[d+0], k4.x, ac0);
      ac1 = fmaf(qu[d+1], k4.y, ac1);
      ac2 = fmaf(qu[d+2], k4.z, ac2);
      ac3 = fmaf(qu[d+3], k4.w, ac3);
    }
    float l = (ac0 + ac1) + (ac2 + ac3);

    const int p = pbase + j;                 // 511 - i + j, always >= 0
    if (p < 1024) {                          // rel_shift validity
      const float* rb = Pr + (size_t)p * 1024 + n * 64;
      float b0 = 0, b1 = 0, b2 = 0, b3 = 0;
      #pragma unroll
      for (int d = 0; d < 64; d += 4) {
        float4 r4 = ld4(rb + d);
        b0 = fmaf(qu[d+0], r4.x, b0);
        b1 = fmaf(qu[d+1], r4.y, b1);
        b2 = fmaf(qu[d+2], r4.z, b2);
        b3 = fmaf(qu[d+3], r4.w, b3);
      }
      l += (b0 + b1) + (b2 + b3) + W2[p * 16 + n];  // qv·kr = qu·kr + (v-u)·kr
    }
    l *= 0.125f;                              // 1/sqrt(64)

    // softmax over the 16 heads (axis=-1 of (i,j,b,n)!)
    float mx = l;
    mx = fmaxf(mx, __shfl_xor(mx, 1, 16));
    mx = fmaxf(mx, __shfl_xor(mx, 2, 16));
    mx = fmaxf(mx, __shfl_xor(mx, 4, 16));
    mx = fmaxf(mx, __shfl_xor(mx, 8, 16));
    float e = __expf(l - mx);
    float s = e;
    s += __shfl_xor(s, 1, 16);
    s += __shfl_xor(s, 2, 16);
    s += __shfl_xor(s, 4, 16);
    s += __shfl_xor(s, 8, 16);
    const float att = e / s;

    const float* vb = Pv + ((size_t)(j * 8 + b)) * 1024 + n * 64;
    #pragma unroll
    for (int d = 0; d < 64; d += 4) {
      float4 v4 = ld4(vb + d);
      o[d+0] = fmaf(att, v4.x, o[d+0]);
      o[d+1] = fmaf(att, v4.y, o[d+1]);
      o[d+2] = fmaf(att, v4.z, o[d+2]);
      o[d+3] = fmaf(att, v4.w, o[d+3]);
    }
  }

  float* ob = O + ((size_t)(i * 8 + b)) * 1024 + n * 64;
  #pragma unroll
  for (int d = 0; d < 64; d += 4) {
    float4 o4;
    o4.x = o[d+0]; o4.y = o[d+1]; o4.z = o[d+2]; o4.w = o[d+3];
    st4(ob + d, o4);
  }
}

// ---------------------------------------------------------------------------
extern "C" void kernel_launch(void* const* d_in, const int* in_sizes, int n_in,
                              void* d_out, int out_size, void* d_ws, size_t ws_size,
                              hipStream_t stream)
{
  const float* x   = (const float*)d_in[0];
  const float* rpe = (const float*)d_in[1];
  // d_in[2] attention_mask: unused by the reference math
  const float* mem = (const float*)d_in[3];
  const float* Wq  = (const float*)d_in[4];
  const float* Wke = (const float*)d_in[5];
  const float* Wv  = (const float*)d_in[6];
  const float* Wkr = (const float*)d_in[7];
  const float* u   = (const float*)d_in[8];
  const float* v   = (const float*)d_in[9];
  const float* Wo  = (const float*)d_in[10];
  const float* bo  = (const float*)d_in[11];
  const int* lp    = (const int*)d_in[12];
  const int* sp    = (const int*)d_in[13];

  float* out = (float*)d_out;
  float* nm  = out + OUT_OFF;          // new_mem region (25165824 floats)

  // Scratch layout
  float* ws = (float*)d_ws;
  size_t off = 0;
  float* Pq = ws + off; off += 4194304;   // 4096 x 1024
  float* Pr = ws + off; off += 1048576;   // 1024 x 1024
  float* W2 = ws + off; off += 16384;     // 1024 x 16
  float* O  = ws + off; off += 4194304;   // 4096 x 1024
  float* Pk;
  float* Pv;
  const size_t needAll = (off + 2ull * 8388608ull) * 4ull;
  if (ws_size >= needAll) {
    Pk = ws + off;          // 8192 x 1024
    Pv = Pk + 8388608;
  } else {
    // Borrow the new_mem region of d_out as scratch; dead before the
    // memories copy below overwrites it (stream-ordered).
    Pk = nm;
    Pv = nm + 8388608;
  }

  dim3 blk(256);
  // Projections
  gemm_k<0><<<dim3(8, 32), blk, 0, stream>>>(x,   nullptr, Wq,  nullptr, nullptr, nullptr, Pq);
  gemm_k<0><<<dim3(8, 8),  blk, 0, stream>>>(rpe, nullptr, Wkr, nullptr, nullptr, nullptr, Pr);
  gemm_k<1><<<dim3(8, 64), blk, 0, stream>>>(x,   mem,     Wke, nullptr, lp, sp, Pk);
  gemm_k<1><<<dim3(8, 64), blk, 0, stream>>>(x,   mem,     Wv,  nullptr, lp, sp, Pv);
  // (v-u)·kr table
  w2_k<<<64, 256, 0, stream>>>(Pr, u, v, W2);
  // Fused attention -> O
  attn_k<<<dim3(32, 8), blk, 0, stream>>>(Pq, Pk, Pv, Pr, W2, u, O);
  // new_mem = memories (then slice overwritten by epilogue GEMM)
  hipMemcpyAsync(nm, mem, (size_t)NM_ELEMS * 4ull, hipMemcpyDeviceToDevice, stream);
  // out = O @ Wo + bo, written to both d_out part-1 and the new_mem slice
  gemm_k<2><<<dim3(8, 32), blk, 0, stream>>>(O, nullptr, Wo, bo, lp, sp, out);
}

// Round 3
// 1143.380 us; speedup vs baseline: 5.4457x; 5.4457x over previous
//
#include <hip/hip_runtime.h>
#include <hip/hip_bf16.h>

// S=512, M=512, B=8, NH=16, HD=64, H=1024, K=1024, LAYERS=2, TOTAL_LEN=1536
#define OUT_OFF 4194304      // B*S*H floats (part-1 of d_out)
#define NM_ELEMS 25165824    // 2*8*1536*1024 floats (part-2: new_mem)

typedef __attribute__((ext_vector_type(8))) short short8;
typedef __attribute__((ext_vector_type(4))) float f32x4;

static __device__ __forceinline__ float4 ld4(const float* p) {
  return *reinterpret_cast<const float4*>(p);
}
static __device__ __forceinline__ void st4(float* p, float4 v) {
  *reinterpret_cast<float4*>(p) = v;
}
static __device__ __forceinline__ short bfbits(float f) {
  __hip_bfloat16 h = __float2bfloat16(f);
  return *reinterpret_cast<short*>(&h);
}

// ---------------------------------------------------------------------------
// fp32 tiled GEMM core, C = A[rows x 1024] @ W[1024 x 1024]
// Row index r of the projection output is ALWAYS the flat row of the
// pre-reshape matmul. Two decompositions of r:
//   gather side (kvx input):  b = r>>10, j = r&1023   (kvx is (B,K,H))
//   output side (post reshape(S/K, B, NH, HD)): i/j = r>>3, b = r&7
// MODE 2: A plain (O), +bias, writes d_out rows AND new_mem slice.
// MODE 3: A plain (rpe), bf16 row-major                 -> KR[p][n*64+d]
// MODE 4: A plain (x),   bf16 (C+u),(C+v)               -> QU/QV[b][n][i][d]
// MODE 5: A gathered kvx, bf16                          -> KE[b][n][j][d]
// MODE 6: A gathered kvx, bf16 transposed (j-contig)    -> Vt[b][n][d][j]
// ---------------------------------------------------------------------------
template<int MODE>
__global__ __launch_bounds__(256)
void gemm_k(const float* __restrict__ A, const float* __restrict__ mem,
            const float* __restrict__ W, const float* __restrict__ P0,
            const float* __restrict__ P1,
            const int* __restrict__ lp, const int* __restrict__ sp,
            float* __restrict__ C, __hip_bfloat16* __restrict__ Cb,
            __hip_bfloat16* __restrict__ Cb2)
{
  __shared__ float As[16][132];
  __shared__ float Bs[16][132];
  const int tid = threadIdx.x;
  const int m0 = blockIdx.y * 128;
  const int n0 = blockIdx.x * 128;
  const int am = tid >> 1;
  const int ak = (tid & 1) * 8;
  const int bk = tid >> 4;
  const int bn = (tid & 15) * 8;
  const int tm = tid & 15;
  const int tn = tid >> 4;
  // MODE 6 micro-tile row remap: thread rows = rb6 + 8*ii (8 consecutive j
  // at fixed batch); otherwise rows = tm*8 + ii.
  const int rb6 = (tm & 7) + 64 * (tm >> 3);

  const float* Arow;
  if (MODE == 5 || MODE == 6) {
    const int r  = m0 + am;         // kvx flat row: b = r>>10, j = r&1023
    const int bb = r >> 10;
    const int j  = r & 1023;
    const int layer = lp[0];
    const int seg   = sp[0];
    if (j < 512)
      Arow = mem + (((size_t)layer * 8 + bb) * 1536 + (size_t)seg * 512 + j) * 1024;
    else
      Arow = A + ((size_t)bb * 512 + (j - 512)) * 1024;
  } else {
    Arow = A + (size_t)(m0 + am) * 1024;
  }

  float acc[8][8] = {};

  for (int k0 = 0; k0 < 1024; k0 += 16) {
    const float4 a0 = ld4(Arow + k0 + ak);
    const float4 a1 = ld4(Arow + k0 + ak + 4);
    const float* wr = W + (size_t)(k0 + bk) * 1024 + n0 + bn;
    const float4 b0 = ld4(wr);
    const float4 b1 = ld4(wr + 4);
    __syncthreads();
    As[ak+0][am] = a0.x; As[ak+1][am] = a0.y; As[ak+2][am] = a0.z; As[ak+3][am] = a0.w;
    As[ak+4][am] = a1.x; As[ak+5][am] = a1.y; As[ak+6][am] = a1.z; As[ak+7][am] = a1.w;
    st4(&Bs[bk][bn],   b0);
    st4(&Bs[bk][bn+4], b1);
    __syncthreads();
    #pragma unroll
    for (int k = 0; k < 16; ++k) {
      float a[8], b8[8];
      if (MODE == 6) {
        #pragma unroll
        for (int ii = 0; ii < 8; ++ii) a[ii] = As[k][rb6 + 8*ii];
      } else {
        *reinterpret_cast<float4*>(&a[0]) = ld4(&As[k][tm*8]);
        *reinterpret_cast<float4*>(&a[4]) = ld4(&As[k][tm*8+4]);
      }
      *reinterpret_cast<float4*>(&b8[0]) = ld4(&Bs[k][tn*8]);
      *reinterpret_cast<float4*>(&b8[4]) = ld4(&Bs[k][tn*8+4]);
      #pragma unroll
      for (int ii = 0; ii < 8; ++ii)
        #pragma unroll
        for (int jj = 0; jj < 8; ++jj)
          acc[ii][jj] = fmaf(a[ii], b8[jj], acc[ii][jj]);
    }
  }

  const int c0 = n0 + tn * 8;          // column base of this thread's tile
  const int nh = c0 >> 6;              // head
  const int dd = c0 & 63;              // d base within head

  if (MODE == 2) {
    const int layer = lp[0];
    const int seg   = sp[0];
    #pragma unroll
    for (int ii = 0; ii < 8; ++ii) {
      const int row = m0 + tm*8 + ii;      // r = b2*512 + s2 (d_out row order)
      const int b2  = row >> 9;
      const int s2  = row & 511;
      const size_t nmrow =
          (((size_t)layer * 8 + b2) * 1536 + 512 + (size_t)seg * 512 + s2) * 1024;
      #pragma unroll
      for (int jq = 0; jq < 2; ++jq) {
        const int col = c0 + jq*4;
        const float4 bi = ld4(P0 + col);
        float4 o4;
        o4.x = acc[ii][jq*4+0] + bi.x;
        o4.y = acc[ii][jq*4+1] + bi.y;
        o4.z = acc[ii][jq*4+2] + bi.z;
        o4.w = acc[ii][jq*4+3] + bi.w;
        st4(C + (size_t)row * 1024 + col, o4);
        st4(C + OUT_OFF + nmrow + col, o4);
      }
    }
  } else if (MODE == 3) {
    #pragma unroll
    for (int ii = 0; ii < 8; ++ii) {
      const int row = m0 + tm*8 + ii;     // p
      short8 s;
      #pragma unroll
      for (int jj = 0; jj < 8; ++jj) s[jj] = bfbits(acc[ii][jj]);
      *reinterpret_cast<short8*>(Cb + (size_t)row * 1024 + c0) = s;
    }
  } else if (MODE == 4) {
    const int i = (m0 + tm*8) >> 3;      // 8 consecutive rows: same i, b = ii
    #pragma unroll
    for (int ii = 0; ii < 8; ++ii) {
      const size_t base = (((size_t)(ii*16 + nh) * 512) + i) * 64 + dd;
      short8 su, sv;
      #pragma unroll
      for (int jj = 0; jj < 8; ++jj) {
        su[jj] = bfbits(acc[ii][jj] + P0[c0 + jj]);
        sv[jj] = bfbits(acc[ii][jj] + P1[c0 + jj]);
      }
      *reinterpret_cast<short8*>(Cb  + base) = su;
      *reinterpret_cast<short8*>(Cb2 + base) = sv;
    }
  } else if (MODE == 5) {
    const int j = (m0 + tm*8) >> 3;      // 8 consecutive rows: same j, b = ii
    #pragma unroll
    for (int ii = 0; ii < 8; ++ii) {
      short8 s;
      #pragma unroll
      for (int jj = 0; jj < 8; ++jj) s[jj] = bfbits(acc[ii][jj]);
      *reinterpret_cast<short8*>(Cb + (((size_t)(ii*16 + nh) * 1024) + j) * 64 + dd) = s;
    }
  } else if (MODE == 6) {
    // thread rows r = m0 + rb6 + 8*ii: b = tm&7 fixed, j = jb + ii consecutive
    const int bg = tm & 7;
    const int jb = (m0 >> 3) + (tm >> 3) * 8;
    #pragma unroll
    for (int jj = 0; jj < 8; ++jj) {
      const int d = dd + jj;
      short8 s;
      #pragma unroll
      for (int ii = 0; ii < 8; ++ii) s[ii] = bfbits(acc[ii][jj]);
      *reinterpret_cast<short8*>(Cb + (((size_t)(bg*16 + nh) * 64) + d) * 1024 + jb) = s;
    }
  }
}

// ---------------------------------------------------------------------------
// Fused MFMA attention. Grid (32 i-tiles, 8 b), block 512 = 8 waves.
// Wave w owns heads 2w, 2w+1; Itile=16 rows; j-tiles of 32.
// AC = QU·KE^T (MFMA); T = QV·KR^T over the 48-wide p band (MFMA); bd
// gathered from T C-frags via shfl (KR rows >=1024 are zero => rel_shift
// mask exact). Cross-head softmax through LDS; PV via MFMA on bf16 att.
// ---------------------------------------------------------------------------
__global__ __launch_bounds__(512, 2)
void attn2(const __hip_bfloat16* __restrict__ QU, const __hip_bfloat16* __restrict__ QV,
           const __hip_bfloat16* __restrict__ KE, const __hip_bfloat16* __restrict__ Vt,
           const __hip_bfloat16* __restrict__ KR, float* __restrict__ O)
{
  __shared__ float Lbuf[16*16*33];              // [n][i][33] logits
  __shared__ __hip_bfloat16 Abuf[2][16*16*40];  // [n][i][40] att bf16, dbuf

  const int b   = blockIdx.y;
  const int i0  = blockIdx.x * 16;
  const int tid = threadIdx.x;
  const int w   = tid >> 6;
  const int l   = tid & 63;
  const int l15 = l & 15;
  const int lg  = l >> 4;

  // Q fragments (row = l15, k-chunk = lg*8 + kf*32), 2 heads x 2 kf
  short8 qu[2][2], qv[2][2];
  #pragma unroll
  for (int hh = 0; hh < 2; ++hh) {
    const int h = 2*w + hh;
    const size_t qb = (((size_t)(b*16 + h) * 512) + i0 + l15) * 64 + lg*8;
    #pragma unroll
    for (int kf = 0; kf < 2; ++kf) {
      qu[hh][kf] = *reinterpret_cast<const short8*>(QU + qb + kf*32);
      qv[hh][kf] = *reinterpret_cast<const short8*>(QV + qb + kf*32);
    }
  }

  f32x4 oacc[2][4];
  #pragma unroll
  for (int hh = 0; hh < 2; ++hh)
    #pragma unroll
    for (int nf = 0; nf < 4; ++nf) oacc[hh][nf] = (f32x4){0.f,0.f,0.f,0.f};

  int buf = 0;
  for (int jt = 0; jt < 32; ++jt) {
    const int j0 = jt * 32;
    const int pb = 496 - i0 + j0;        // band base: p = pb + idx, idx in [0,47]

    // ---- phase 1: logits ----
    #pragma unroll
    for (int hh = 0; hh < 2; ++hh) {
      const int h = 2*w + hh;
      f32x4 ac[2]; ac[0] = (f32x4){0,0,0,0}; ac[1] = (f32x4){0,0,0,0};
      #pragma unroll
      for (int jf = 0; jf < 2; ++jf)
        #pragma unroll
        for (int kf = 0; kf < 2; ++kf) {
          const short8 kb = *reinterpret_cast<const short8*>(
            KE + (((size_t)(b*16 + h) * 1024) + j0 + jf*16 + l15) * 64 + kf*32 + lg*8);
          ac[jf] = __builtin_amdgcn_mfma_f32_16x16x32_bf16(qu[hh][kf], kb, ac[jf], 0, 0, 0);
        }
      f32x4 tf[3];
      tf[0] = (f32x4){0,0,0,0}; tf[1] = (f32x4){0,0,0,0}; tf[2] = (f32x4){0,0,0,0};
      #pragma unroll
      for (int nf = 0; nf < 3; ++nf)
        #pragma unroll
        for (int kf = 0; kf < 2; ++kf) {
          const short8 rb = *reinterpret_cast<const short8*>(
            KR + ((size_t)(pb + nf*16 + l15)) * 1024 + h*64 + kf*32 + lg*8);
          tf[nf] = __builtin_amdgcn_mfma_f32_16x16x32_bf16(qv[hh][kf], rb, tf[nf], 0, 0, 0);
        }
      // gather bd[ip, jl] = T[ip][15 - ip + jl] from C-frags via shfl
      #pragma unroll
      for (int jf = 0; jf < 2; ++jf)
        #pragma unroll
        for (int r = 0; r < 4; ++r) {
          const int ip  = lg*4 + r;
          const int idx = 15 - ip + jf*16 + l15;         // 0..46
          const int nf  = idx >> 4;
          const int Ls  = lg*16 + (idx & 15);
          const float v0 = __shfl(tf[0][r], Ls, 64);
          const float v1 = __shfl(tf[1][r], Ls, 64);
          const float v2 = __shfl(tf[2][r], Ls, 64);
          const float bd = (nf == 0) ? v0 : ((nf == 1) ? v1 : v2);
          Lbuf[(h*16 + ip)*33 + jf*16 + l15] = 0.125f * (ac[jf][r] + bd);
        }
    }
    __syncthreads();

    // ---- phase 2: softmax over 16 heads; thread t -> (i = t>>5, j = t&31)
    {
      const int si = tid >> 5, sj = tid & 31;
      float vals[16];
      float m = -3.0e38f;
      #pragma unroll
      for (int n = 0; n < 16; ++n) {
        vals[n] = Lbuf[(n*16 + si)*33 + sj];
        m = fmaxf(m, vals[n]);
      }
      float s = 0.f;
      #pragma unroll
      for (int n = 0; n < 16; ++n) { vals[n] = __expf(vals[n] - m); s += vals[n]; }
      const float rinv = 1.0f / s;
      #pragma unroll
      for (int n = 0; n < 16; ++n) {
        __hip_bfloat16 hv = __float2bfloat16(vals[n] * rinv);
        Abuf[buf][(n*16 + si)*40 + sj] = hv;
      }
    }
    __syncthreads();

    // ---- phase 3: PV ----
    #pragma unroll
    for (int hh = 0; hh < 2; ++hh) {
      const int h = 2*w + hh;
      const short8 af = *reinterpret_cast<const short8*>(
          &Abuf[buf][(h*16 + l15)*40 + lg*8]);
      #pragma unroll
      for (int nf = 0; nf < 4; ++nf) {
        const short8 vb = *reinterpret_cast<const short8*>(
          Vt + (((size_t)(b*16 + h) * 64) + nf*16 + l15) * 1024 + j0 + lg*8);
        oacc[hh][nf] = __builtin_amdgcn_mfma_f32_16x16x32_bf16(af, vb, oacc[hh][nf], 0, 0, 0);
      }
    }
    buf ^= 1;
  }

  // store O rows r = i*8+b, cols h*64 + nf*16 + l15
  #pragma unroll
  for (int hh = 0; hh < 2; ++hh) {
    const int h = 2*w + hh;
    #pragma unroll
    for (int nf = 0; nf < 4; ++nf)
      #pragma unroll
      for (int r = 0; r < 4; ++r) {
        const int i = i0 + lg*4 + r;
        O[((size_t)(i*8 + b)) * 1024 + h*64 + nf*16 + l15] = oacc[hh][nf][r];
      }
  }
}

// ---------------------------------------------------------------------------
extern "C" void kernel_launch(void* const* d_in, const int* in_sizes, int n_in,
                              void* d_out, int out_size, void* d_ws, size_t ws_size,
                              hipStream_t stream)
{
  const float* x   = (const float*)d_in[0];
  const float* rpe = (const float*)d_in[1];
  const float* mem = (const float*)d_in[3];
  const float* Wq  = (const float*)d_in[4];
  const float* Wke = (const float*)d_in[5];
  const float* Wv  = (const float*)d_in[6];
  const float* Wkr = (const float*)d_in[7];
  const float* u   = (const float*)d_in[8];
  const float* v   = (const float*)d_in[9];
  const float* Wo  = (const float*)d_in[10];
  const float* bo  = (const float*)d_in[11];
  const int* lp    = (const int*)d_in[12];
  const int* sp    = (const int*)d_in[13];

  float* out = (float*)d_out;
  float* nm  = out + OUT_OFF;

  // ws layout (float units): QU 2097152 | QV 2097152 | KR 786432 | O 4194304
  float* ws = (float*)d_ws;
  __hip_bfloat16* QUb = (__hip_bfloat16*)ws;
  __hip_bfloat16* QVb = (__hip_bfloat16*)(ws + 2097152);
  __hip_bfloat16* KRb = (__hip_bfloat16*)(ws + 4194304);   // [1536][1024] bf16
  float*          O   = ws + 4980736;
  // KE/Vt borrow the new_mem region (dead before the memcpy below)
  __hip_bfloat16* KEb = (__hip_bfloat16*)nm;               // 16 MB
  __hip_bfloat16* Vtb = (__hip_bfloat16*)(nm + 4194304);   // 16 MB

  dim3 blk(256);
  // zero KR pad rows 1024..1535 (makes rel_shift masking exact)
  hipMemsetAsync((void*)(KRb + (size_t)1024*1024), 0, (size_t)512*1024*2, stream);

  gemm_k<3><<<dim3(8, 8),  blk, 0, stream>>>(rpe, nullptr, Wkr, nullptr, nullptr, lp, sp, nullptr, KRb, nullptr);
  gemm_k<4><<<dim3(8, 32), blk, 0, stream>>>(x,   nullptr, Wq,  u,       v,       lp, sp, nullptr, QUb, QVb);
  gemm_k<5><<<dim3(8, 64), blk, 0, stream>>>(x,   mem,     Wke, nullptr, nullptr, lp, sp, nullptr, KEb, nullptr);
  gemm_k<6><<<dim3(8, 64), blk, 0, stream>>>(x,   mem,     Wv,  nullptr, nullptr, lp, sp, nullptr, Vtb, nullptr);

  attn2<<<dim3(32, 8), dim3(512), 0, stream>>>(QUb, QVb, KEb, Vtb, KRb, O);

  hipMemcpyAsync(nm, mem, (size_t)NM_ELEMS * 4ull, hipMemcpyDeviceToDevice, stream);

  gemm_k<2><<<dim3(8, 32), blk, 0, stream>>>(O, nullptr, Wo, bo, nullptr, lp, sp, out, nullptr, nullptr);
}

// Round 4
// 436.383 us; speedup vs baseline: 14.2683x; 2.6201x over previous
//
#include <hip/hip_runtime.h>
#include <hip/hip_bf16.h>

// S=512, M=512, B=8, NH=16, HD=64, H=1024, K=1024, LAYERS=2, TOTAL_LEN=1536
#define OUT_OFF 4194304      // B*S*H floats (part-1 of d_out)
#define NM_ELEMS 25165824    // 2*8*1536*1024 floats (part-2: new_mem)

typedef __attribute__((ext_vector_type(8))) short short8;
typedef __attribute__((ext_vector_type(4))) float f32x4;

static __device__ __forceinline__ float4 ld4(const float* p) {
  return *reinterpret_cast<const float4*>(p);
}
static __device__ __forceinline__ short bfbits(float f) {
  __hip_bfloat16 h = __float2bfloat16(f);
  return *reinterpret_cast<short*>(&h);
}
// async global->LDS, 16B per lane; lds base must be wave-uniform.
static __device__ __forceinline__ void gload16(const void* g, void* l) {
  __builtin_amdgcn_global_load_lds(
      (const __attribute__((address_space(1))) void*)g,
      (__attribute__((address_space(3))) void*)l, 16, 0, 0);
}

// ---------------------------------------------------------------------------
// Pre-pass 1: weight transpose+convert. Wt[n][k] = bf16(W[k][n]), 1024x1024.
// grid (16,16,5) block 256. LDS tile 64x64.
// ---------------------------------------------------------------------------
__global__ __launch_bounds__(256)
void cw_k(const float* __restrict__ W0, const float* __restrict__ W1,
          const float* __restrict__ W2, const float* __restrict__ W3,
          const float* __restrict__ W4,
          __hip_bfloat16* __restrict__ T0, __hip_bfloat16* __restrict__ T1,
          __hip_bfloat16* __restrict__ T2, __hip_bfloat16* __restrict__ T3,
          __hip_bfloat16* __restrict__ T4)
{
  const float* W; __hip_bfloat16* T;
  switch (blockIdx.z) {
    case 0: W = W0; T = T0; break;
    case 1: W = W1; T = T1; break;
    case 2: W = W2; T = T2; break;
    case 3: W = W3; T = T3; break;
    default: W = W4; T = T4; break;
  }
  __shared__ short S[64][72];
  const int t = threadIdx.x;
  const int n0 = blockIdx.x * 64, k0 = blockIdx.y * 64;
  #pragma unroll
  for (int it = 0; it < 2; ++it) {
    const int kl = (t >> 3) + it * 32;
    const int n8 = (t & 7) * 8;
    const float* src = W + (size_t)(k0 + kl) * 1024 + n0 + n8;
    const float4 f0 = ld4(src), f1 = ld4(src + 4);
    short8 s;
    s[0]=bfbits(f0.x); s[1]=bfbits(f0.y); s[2]=bfbits(f0.z); s[3]=bfbits(f0.w);
    s[4]=bfbits(f1.x); s[5]=bfbits(f1.y); s[6]=bfbits(f1.z); s[7]=bfbits(f1.w);
    *reinterpret_cast<short8*>(&S[kl][n8]) = s;
  }
  __syncthreads();
  #pragma unroll
  for (int it = 0; it < 2; ++it) {
    const int nl = (t >> 3) + it * 32;
    const int k8 = (t & 7) * 8;
    short8 s;
    #pragma unroll
    for (int e = 0; e < 8; ++e) s[e] = S[k8 + e][nl];
    *reinterpret_cast<short8*>((short*)T + (size_t)(n0 + nl) * 1024 + k0 + k8) = s;
  }
}

// ---------------------------------------------------------------------------
// Pre-pass 2: Kvx[r][k] bf16, r = b*1024 + j gathered from mem slice / x.
// ---------------------------------------------------------------------------
__global__ __launch_bounds__(256)
void ckvx_k(const float* __restrict__ x, const float* __restrict__ mem,
            const int* __restrict__ lp, const int* __restrict__ sp,
            __hip_bfloat16* __restrict__ Kvx)
{
  const size_t t = (size_t)blockIdx.x * 256 + threadIdx.x;
  const int r = (int)(t >> 7);
  const int c = (int)(t & 127) * 8;
  const int b = r >> 10, j = r & 1023;
  const float* src = (j < 512)
    ? mem + (((size_t)lp[0] * 8 + b) * 1536 + (size_t)sp[0] * 512 + j) * 1024 + c
    : x + ((size_t)b * 512 + (j - 512)) * 1024 + c;
  const float4 f0 = ld4(src), f1 = ld4(src + 4);
  short8 s;
  s[0]=bfbits(f0.x); s[1]=bfbits(f0.y); s[2]=bfbits(f0.z); s[3]=bfbits(f0.w);
  s[4]=bfbits(f1.x); s[5]=bfbits(f1.y); s[6]=bfbits(f1.z); s[7]=bfbits(f1.w);
  *reinterpret_cast<short8*>((short*)Kvx + (size_t)r * 1024 + c) = s;
}

// Pre-pass 3: rpe fp32 -> bf16 elementwise (1024x1024)
__global__ __launch_bounds__(256)
void crpe_k(const float* __restrict__ R, __hip_bfloat16* __restrict__ Rb)
{
  const size_t t = ((size_t)blockIdx.x * 256 + threadIdx.x) * 8;
  const float4 f0 = ld4(R + t), f1 = ld4(R + t + 4);
  short8 s;
  s[0]=bfbits(f0.x); s[1]=bfbits(f0.y); s[2]=bfbits(f0.z); s[3]=bfbits(f0.w);
  s[4]=bfbits(f1.x); s[5]=bfbits(f1.y); s[6]=bfbits(f1.z); s[7]=bfbits(f1.w);
  *reinterpret_cast<short8*>((short*)Rb + t) = s;
}

// ---------------------------------------------------------------------------
// MFMA GEMM: C[M x 1024] = A[M x 1024] @ Wt^T  (Wt is [n][k] bf16).
// 128x128 tile, BK=64, 256 thr = 4 waves, each wave 64x64 (4x4 16x16 frags).
// global_load_lds(16B) staging, 2 barriers per K-step (m97 structure).
// MODE 3: Cb row-major [row][col]                      (KR)
// MODE 4: row->(i=r>>3,b=r&7); Cb=acc+u, Cb2=acc+v     (QU/QV [b][n][i][d])
// MODE 5: row->(j=r>>3,b=r&7); Cb                      (KE/VE [b][n][j][d])
// MODE 2: fp32 out rows + new_mem slice, +bias          (final)
// MODE 4 input remap: A row r comes from Kvx row (r>>9)*1024+512+(r&511).
// ---------------------------------------------------------------------------
template<int MODE>
__global__ __launch_bounds__(256)
void mgemm(const __hip_bfloat16* __restrict__ A,
           const __hip_bfloat16* __restrict__ Wt,
           const float* __restrict__ P0, const float* __restrict__ P1,
           const int* __restrict__ lp, const int* __restrict__ sp,
           __hip_bfloat16* __restrict__ Cb, __hip_bfloat16* __restrict__ Cb2,
           float* __restrict__ C)
{
  __shared__ __align__(16) short As[128 * 64];
  __shared__ __align__(16) short Bs[128 * 64];
  const int tid = threadIdx.x;
  const int w   = tid >> 6;
  const int l   = tid & 63;
  const int l15 = l & 15, lg = l >> 4;
  const int m0 = blockIdx.y * 128;
  const int n0 = blockIdx.x * 128;
  const int wr = (w >> 1) * 64;
  const int wc = (w & 1) * 64;

  f32x4 acc[4][4];
  #pragma unroll
  for (int mi = 0; mi < 4; ++mi)
    #pragma unroll
    for (int ni = 0; ni < 4; ++ni) acc[mi][ni] = (f32x4){0.f, 0.f, 0.f, 0.f};

  const int srow = (l >> 3);          // staging row within 8-row segment
  const int scol = (l & 7) * 8;       // staging k-offset (8 bf16 = 16B)

  for (int k0 = 0; k0 < 1024; k0 += 64) {
    if (k0) __syncthreads();
    // stage A and B tiles: 4 issues each per wave
    #pragma unroll
    for (int q = 0; q < 4; ++q) {
      const int seg = w * 32 + q * 8;
      const int ra = m0 + seg + srow;
      size_t aoff;
      if (MODE == 4)
        aoff = ((size_t)(ra >> 9) * 1024 + 512 + (ra & 511)) * 1024;
      else
        aoff = (size_t)ra * 1024;
      gload16((const short*)A + aoff + k0 + scol, &As[seg * 64]);
      const int rb = n0 + seg + srow;
      gload16((const short*)Wt + (size_t)rb * 1024 + k0 + scol, &Bs[seg * 64]);
    }
    __syncthreads();   // drains vmcnt before barrier (compiler-inserted)
    #pragma unroll
    for (int kk = 0; kk < 2; ++kk) {
      short8 a[4], bf[4];
      #pragma unroll
      for (int mi = 0; mi < 4; ++mi)
        a[mi] = *reinterpret_cast<const short8*>(
            &As[(wr + mi * 16 + l15) * 64 + kk * 32 + lg * 8]);
      #pragma unroll
      for (int ni = 0; ni < 4; ++ni)
        bf[ni] = *reinterpret_cast<const short8*>(
            &Bs[(wc + ni * 16 + l15) * 64 + kk * 32 + lg * 8]);
      #pragma unroll
      for (int mi = 0; mi < 4; ++mi)
        #pragma unroll
        for (int ni = 0; ni < 4; ++ni)
          acc[mi][ni] = __builtin_amdgcn_mfma_f32_16x16x32_bf16(
              a[mi], bf[ni], acc[mi][ni], 0, 0, 0);
    }
  }

  // epilogue: row = m0+wr+mi*16+lg*4+rr, col = n0+wc+ni*16+l15
  #pragma unroll
  for (int mi = 0; mi < 4; ++mi) {
    const int rbase = m0 + wr + mi * 16 + lg * 4;
    #pragma unroll
    for (int ni = 0; ni < 4; ++ni) {
      const int col = n0 + wc + ni * 16 + l15;
      const int nh = col >> 6, dd = col & 63;
      #pragma unroll
      for (int rr = 0; rr < 4; ++rr) {
        const int row = rbase + rr;
        const float val = acc[mi][ni][rr];
        if (MODE == 3) {
          Cb[(size_t)row * 1024 + col] = __float2bfloat16(val);
        } else if (MODE == 4) {
          const int i = row >> 3, bb = row & 7;
          const size_t o = (((size_t)(bb * 16 + nh) * 512) + i) * 64 + dd;
          Cb [o] = __float2bfloat16(val + P0[col]);
          Cb2[o] = __float2bfloat16(val + P1[col]);
        } else if (MODE == 5) {
          const int j = row >> 3, bb = row & 7;
          Cb[(((size_t)(bb * 16 + nh) * 1024) + j) * 64 + dd] =
              __float2bfloat16(val);
        } else if (MODE == 2) {
          const float o = val + P0[col];
          C[(size_t)row * 1024 + col] = o;
          const int b2 = row >> 9, s2 = row & 511;
          C[OUT_OFF +
            (((size_t)lp[0] * 8 + b2) * 1536 + 512 + (size_t)sp[0] * 512 + s2) *
                1024 + col] = o;
        }
      }
    }
  }
}

// ---------------------------------------------------------------------------
// VE[b][n][j][d] -> Vt[b][n][d][j]  (bf16). grid (16 j-tiles, 128 bn).
// ---------------------------------------------------------------------------
__global__ __launch_bounds__(256)
void tr_k(const __hip_bfloat16* __restrict__ VE, __hip_bfloat16* __restrict__ Vt)
{
  __shared__ short T[64][72];
  const int t = threadIdx.x;
  const int j0 = blockIdx.x * 64;
  const int bn = blockIdx.y;
  #pragma unroll
  for (int it = 0; it < 2; ++it) {
    const int jl = (t >> 3) + it * 32;
    const int d8 = (t & 7) * 8;
    *reinterpret_cast<short8*>(&T[jl][d8]) =
        *reinterpret_cast<const short8*>(
            (const short*)VE + ((size_t)bn * 1024 + j0 + jl) * 64 + d8);
  }
  __syncthreads();
  #pragma unroll
  for (int it = 0; it < 2; ++it) {
    const int dl = (t >> 3) + it * 32;
    const int j8 = (t & 7) * 8;
    short8 s;
    #pragma unroll
    for (int e = 0; e < 8; ++e) s[e] = T[j8 + e][dl];
    *reinterpret_cast<short8*>(
        (short*)Vt + ((size_t)bn * 64 + dl) * 1024 + j0 + j8) = s;
  }
}

// ---------------------------------------------------------------------------
// Fused MFMA attention (round-3-proven), now emitting bf16 O.
// ---------------------------------------------------------------------------
__global__ __launch_bounds__(512, 2)
void attn2(const __hip_bfloat16* __restrict__ QU, const __hip_bfloat16* __restrict__ QV,
           const __hip_bfloat16* __restrict__ KE, const __hip_bfloat16* __restrict__ Vt,
           const __hip_bfloat16* __restrict__ KR, __hip_bfloat16* __restrict__ Ob)
{
  __shared__ float Lbuf[16*16*33];              // [n][i][33] logits
  __shared__ __hip_bfloat16 Abuf[2][16*16*40];  // [n][i][40] att bf16, dbuf

  const int b   = blockIdx.y;
  const int i0  = blockIdx.x * 16;
  const int tid = threadIdx.x;
  const int w   = tid >> 6;
  const int l   = tid & 63;
  const int l15 = l & 15;
  const int lg  = l >> 4;

  short8 qu[2][2], qv[2][2];
  #pragma unroll
  for (int hh = 0; hh < 2; ++hh) {
    const int h = 2*w + hh;
    const size_t qb = (((size_t)(b*16 + h) * 512) + i0 + l15) * 64 + lg*8;
    #pragma unroll
    for (int kf = 0; kf < 2; ++kf) {
      qu[hh][kf] = *reinterpret_cast<const short8*>(QU + qb + kf*32);
      qv[hh][kf] = *reinterpret_cast<const short8*>(QV + qb + kf*32);
    }
  }

  f32x4 oacc[2][4];
  #pragma unroll
  for (int hh = 0; hh < 2; ++hh)
    #pragma unroll
    for (int nf = 0; nf < 4; ++nf) oacc[hh][nf] = (f32x4){0.f,0.f,0.f,0.f};

  int buf = 0;
  for (int jt = 0; jt < 32; ++jt) {
    const int j0 = jt * 32;
    const int pb = 496 - i0 + j0;

    #pragma unroll
    for (int hh = 0; hh < 2; ++hh) {
      const int h = 2*w + hh;
      f32x4 ac[2]; ac[0] = (f32x4){0,0,0,0}; ac[1] = (f32x4){0,0,0,0};
      #pragma unroll
      for (int jf = 0; jf < 2; ++jf)
        #pragma unroll
        for (int kf = 0; kf < 2; ++kf) {
          const short8 kb = *reinterpret_cast<const short8*>(
            KE + (((size_t)(b*16 + h) * 1024) + j0 + jf*16 + l15) * 64 + kf*32 + lg*8);
          ac[jf] = __builtin_amdgcn_mfma_f32_16x16x32_bf16(qu[hh][kf], kb, ac[jf], 0, 0, 0);
        }
      f32x4 tf[3];
      tf[0] = (f32x4){0,0,0,0}; tf[1] = (f32x4){0,0,0,0}; tf[2] = (f32x4){0,0,0,0};
      #pragma unroll
      for (int nf = 0; nf < 3; ++nf)
        #pragma unroll
        for (int kf = 0; kf < 2; ++kf) {
          const short8 rb = *reinterpret_cast<const short8*>(
            KR + ((size_t)(pb + nf*16 + l15)) * 1024 + h*64 + kf*32 + lg*8);
          tf[nf] = __builtin_amdgcn_mfma_f32_16x16x32_bf16(qv[hh][kf], rb, tf[nf], 0, 0, 0);
        }
      #pragma unroll
      for (int jf = 0; jf < 2; ++jf)
        #pragma unroll
        for (int r = 0; r < 4; ++r) {
          const int ip  = lg*4 + r;
          const int idx = 15 - ip + jf*16 + l15;         // 0..46
          const int nf  = idx >> 4;
          const int Ls  = lg*16 + (idx & 15);
          const float v0 = __shfl(tf[0][r], Ls, 64);
          const float v1 = __shfl(tf[1][r], Ls, 64);
          const float v2 = __shfl(tf[2][r], Ls, 64);
          const float bd = (nf == 0) ? v0 : ((nf == 1) ? v1 : v2);
          Lbuf[(h*16 + ip)*33 + jf*16 + l15] = 0.125f * (ac[jf][r] + bd);
        }
    }
    __syncthreads();

    {
      const int si = tid >> 5, sj = tid & 31;
      float vals[16];
      float m = -3.0e38f;
      #pragma unroll
      for (int n = 0; n < 16; ++n) {
        vals[n] = Lbuf[(n*16 + si)*33 + sj];
        m = fmaxf(m, vals[n]);
      }
      float s = 0.f;
      #pragma unroll
      for (int n = 0; n < 16; ++n) { vals[n] = __expf(vals[n] - m); s += vals[n]; }
      const float rinv = 1.0f / s;
      #pragma unroll
      for (int n = 0; n < 16; ++n)
        Abuf[buf][(n*16 + si)*40 + sj] = __float2bfloat16(vals[n] * rinv);
    }
    __syncthreads();

    #pragma unroll
    for (int hh = 0; hh < 2; ++hh) {
      const int h = 2*w + hh;
      const short8 af = *reinterpret_cast<const short8*>(
          &Abuf[buf][(h*16 + l15)*40 + lg*8]);
      #pragma unroll
      for (int nf = 0; nf < 4; ++nf) {
        const short8 vb = *reinterpret_cast<const short8*>(
          Vt + (((size_t)(b*16 + h) * 64) + nf*16 + l15) * 1024 + j0 + lg*8);
        oacc[hh][nf] = __builtin_amdgcn_mfma_f32_16x16x32_bf16(af, vb, oacc[hh][nf], 0, 0, 0);
      }
    }
    buf ^= 1;
  }

  #pragma unroll
  for (int hh = 0; hh < 2; ++hh) {
    const int h = 2*w + hh;
    #pragma unroll
    for (int nf = 0; nf < 4; ++nf)
      #pragma unroll
      for (int r = 0; r < 4; ++r) {
        const int i = i0 + lg*4 + r;
        Ob[((size_t)(i*8 + b)) * 1024 + h*64 + nf*16 + l15] =
            __float2bfloat16(oacc[hh][nf][r]);
      }
  }
}

// ---------------------------------------------------------------------------
extern "C" void kernel_launch(void* const* d_in, const int* in_sizes, int n_in,
                              void* d_out, int out_size, void* d_ws, size_t ws_size,
                              hipStream_t stream)
{
  const float* x   = (const float*)d_in[0];
  const float* rpe = (const float*)d_in[1];
  const float* mem = (const float*)d_in[3];
  const float* Wq  = (const float*)d_in[4];
  const float* Wke = (const float*)d_in[5];
  const float* Wv  = (const float*)d_in[6];
  const float* Wkr = (const float*)d_in[7];
  const float* u   = (const float*)d_in[8];
  const float* v   = (const float*)d_in[9];
  const float* Wo  = (const float*)d_in[10];
  const float* bo  = (const float*)d_in[11];
  const int* lp    = (const int*)d_in[12];
  const int* sp    = (const int*)d_in[13];

  float* out = (float*)d_out;
  float* nm  = out + OUT_OFF;

  // ws layout (float offsets), total 32.5 MB
  float* ws = (float*)d_ws;
  __hip_bfloat16* QUb = (__hip_bfloat16*)(ws);             // 4.19M elems
  __hip_bfloat16* QVb = (__hip_bfloat16*)(ws + 2097152);
  __hip_bfloat16* KRb = (__hip_bfloat16*)(ws + 4194304);   // [1536][1024]
  __hip_bfloat16* Ob  = (__hip_bfloat16*)(ws + 4980736);   // [4096][1024]
  __hip_bfloat16* Rb  = (__hip_bfloat16*)(ws + 7077888);   // [1024][1024]
  __hip_bfloat16* WtO = (__hip_bfloat16*)(ws + 7602176);   // [1024][1024]
  // new_mem region scratch (dead before the memcpy)
  __hip_bfloat16* Kvx = (__hip_bfloat16*)(nm);              // [8192][1024]
  __hip_bfloat16* KEb = (__hip_bfloat16*)(nm + 4194304);
  __hip_bfloat16* VEb = (__hip_bfloat16*)(nm + 8388608);
  __hip_bfloat16* Vtb = (__hip_bfloat16*)(nm + 12582912);
  __hip_bfloat16* WtQ = (__hip_bfloat16*)(nm + 16777216);
  __hip_bfloat16* WtK = (__hip_bfloat16*)(nm + 17301504);
  __hip_bfloat16* WtV = (__hip_bfloat16*)(nm + 17825792);
  __hip_bfloat16* WtR = (__hip_bfloat16*)(nm + 18350080);

  dim3 blk(256);
  // zero KR pad rows 1024..1535 (rel_shift masking)
  hipMemsetAsync((void*)(KRb + (size_t)1024*1024), 0, (size_t)512*1024*2, stream);

  cw_k <<<dim3(16,16,5), blk, 0, stream>>>(Wq, Wke, Wv, Wkr, Wo,
                                           WtQ, WtK, WtV, WtR, WtO);
  ckvx_k<<<4096, blk, 0, stream>>>(x, mem, lp, sp, Kvx);
  crpe_k<<<512,  blk, 0, stream>>>(rpe, Rb);

  mgemm<3><<<dim3(8, 8),  blk, 0, stream>>>(Rb,  WtR, nullptr, nullptr, lp, sp, KRb, nullptr, nullptr);
  mgemm<4><<<dim3(8, 32), blk, 0, stream>>>(Kvx, WtQ, u, v,             lp, sp, QUb, QVb,     nullptr);
  mgemm<5><<<dim3(8, 64), blk, 0, stream>>>(Kvx, WtK, nullptr, nullptr, lp, sp, KEb, nullptr, nullptr);
  mgemm<5><<<dim3(8, 64), blk, 0, stream>>>(Kvx, WtV, nullptr, nullptr, lp, sp, VEb, nullptr, nullptr);

  tr_k<<<dim3(16, 128), blk, 0, stream>>>(VEb, Vtb);

  attn2<<<dim3(32, 8), dim3(512), 0, stream>>>(QUb, QVb, KEb, Vtb, KRb, Ob);

  hipMemcpyAsync(nm, mem, (size_t)NM_ELEMS * 4ull, hipMemcpyDeviceToDevice, stream);

  mgemm<2><<<dim3(8, 32), blk, 0, stream>>>(Ob, WtO, bo, nullptr, lp, sp, nullptr, nullptr, out);
}